// Round 1
// baseline (9666.632 us; speedup 1.0000x reference)
//
#include <hip/hip_runtime.h>

// Problem constants
#define TT   64     // seq len
#define NB   8      // batch
#define NN   512    // nodes
#define HID  128    // lstm hidden
#define G4   512    // 4*HID
#define EE   8192   // edges
#define SBLK 16     // sequences per block
#define NTHR 512    // threads per block (8 waves)
#define KC   32     // K-chunk size
#define WP   36     // Wbuf row pitch (floats): 16B-aligned, de-conflicted
#define HP   132    // hbuf row pitch: 16B-aligned, 2-way max
#define GP   516    // gates row pitch

__device__ __forceinline__ float sigf(float x){ return 1.0f/(1.0f+expf(-x)); }

// Fused 3-layer LSTM scan. Each block owns 16 independent sequences and runs
// all 64 timesteps for all 3 layers. Weights streamed from L2 in 64KB chunks
// (register prefetch -> LDS), h-state in LDS, c-state in registers.
__global__ __launch_bounds__(NTHR,2) void lstm_scan(
    const float* __restrict__ x,
    const float* __restrict__ wih0, const float* __restrict__ whh0,
    const float* __restrict__ bih0, const float* __restrict__ bhh0,
    const float* __restrict__ wih1, const float* __restrict__ whh1,
    const float* __restrict__ bih1, const float* __restrict__ bhh1,
    const float* __restrict__ wih2, const float* __restrict__ whh2,
    const float* __restrict__ bih2, const float* __restrict__ bhh2,
    float* __restrict__ feats)
{
  __shared__ float Wbuf[G4*WP];          // 72 KB staged weight chunk
  __shared__ float hbuf[3*SBLK*HP];      // 24.75 KB h per layer
  __shared__ float gates[SBLK*GP];       // 32.25 KB gate preacts
  __shared__ float bsum[3*G4];           // b_ih + b_hh per layer
  __shared__ float wih0s[G4];
  __shared__ float xbuf[SBLK];

  const int tid = threadIdx.x;
  const int si  = tid & 15;              // sequence within block
  const int gi  = tid >> 4;              // gate group 0..31
  const int s0  = blockIdx.x * SBLK;
  const int b   = s0 >> 9;               // batch (N=512)
  const int n0  = s0 & (NN-1);

  for (int i = tid; i < 3*SBLK*HP; i += NTHR) hbuf[i] = 0.0f;
  for (int i = tid; i < G4; i += NTHR){
    bsum[i]      = bih0[i] + bhh0[i];
    bsum[G4+i]   = bih1[i] + bhh1[i];
    bsum[2*G4+i] = bih2[i] + bhh2[i];
    wih0s[i]     = wih0[i];
  }

  float creg[3][4];
  #pragma unroll
  for (int l=0;l<3;l++){ creg[l][0]=creg[l][1]=creg[l][2]=creg[l][3]=0.f; }

  // chunk schedule per step: 0-3 whh0 | 4-7 wih1 | 8-11 whh1 | 12-15 wih2 | 16-19 whh2
  auto chunk_base = [&](int cc)->const float*{
    const float* p;
    switch (cc>>2){
      case 0: p = whh0; break;
      case 1: p = wih1; break;
      case 2: p = whh1; break;
      case 3: p = wih2; break;
      default: p = whh2; break;
    }
    return p + (cc&3)*KC;
  };

  float4 pf[8];
  auto load_pf = [&](int cc){
    const float* p = chunk_base(cc);
    #pragma unroll
    for (int i=0;i<8;i++){
      int q = tid + NTHR*i;
      int g = q >> 3, kk = (q&7)<<2;
      pf[i] = *(const float4*)(p + g*HID + kk);
    }
  };
  load_pf(0);
  __syncthreads();

  float acc[16];
  #pragma unroll 1
  for (int t=0;t<TT;t++){
    if (tid < SBLK) xbuf[tid] = x[(b*TT + t)*NN + n0 + tid];
    #pragma unroll
    for (int layer=0; layer<3; layer++){
      #pragma unroll
      for (int j=0;j<16;j++) acc[j] = bsum[layer*G4 + gi + 32*j];
      const int ccbase = (layer==0)?0:(layer==1)?4:12;
      const int ncc    = (layer==0)?4:8;
      #pragma unroll 1
      for (int c=0;c<ncc;c++){
        const int cc = ccbase + c;
        __syncthreads();                  // Wbuf free
        #pragma unroll
        for (int i=0;i<8;i++){            // stage prefetched chunk
          int q = tid + NTHR*i;
          int g = q>>3, kk = (q&7)<<2;
          *(float4*)&Wbuf[g*WP + kk] = pf[i];
        }
        int nx = cc + 1; if (nx == 20) nx = 0;
        load_pf(nx);                      // prefetch next chunk (latency hidden by compute)
        __syncthreads();                  // Wbuf ready
        // input vector: cc<8 -> h0 region covers (whh0, wih1); 8-15 -> h1; 16-19 -> h2
        const int hb = (cc<8)?0:(cc<16)?1:2;
        const float* hrow = &hbuf[hb*SBLK*HP + si*HP + (cc&3)*KC];
        float4 hv[8];
        #pragma unroll
        for (int kg=0;kg<8;kg++) hv[kg] = *(const float4*)(hrow + 4*kg);
        #pragma unroll
        for (int j=0;j<16;j++){
          const float* wrow = &Wbuf[(gi + 32*j)*WP];
          float a0 = acc[j];
          #pragma unroll
          for (int kg=0;kg<8;kg++){
            float4 w4 = *(const float4*)(wrow + 4*kg);
            a0 += hv[kg].x*w4.x + hv[kg].y*w4.y + hv[kg].z*w4.z + hv[kg].w*w4.w;
          }
          acc[j] = a0;
        }
      }
      if (layer==0){                      // scalar input projection for layer 0
        float xv = xbuf[si];
        #pragma unroll
        for (int j=0;j<16;j++) acc[j] += xv * wih0s[gi + 32*j];
      }
      #pragma unroll
      for (int j=0;j<16;j++) gates[si*GP + gi + 32*j] = acc[j];
      __syncthreads();
      // cell update: 4 cells per thread, c-state in registers
      #pragma unroll
      for (int i=0;i<4;i++){
        int id = tid + NTHR*i;
        int s = id >> 7, u = id & 127;
        float iv = gates[s*GP + u];
        float fv = gates[s*GP + 128 + u];
        float gv = gates[s*GP + 256 + u];
        float ov = gates[s*GP + 384 + u];
        float cn = sigf(fv)*creg[layer][i] + sigf(iv)*tanhf(gv);
        creg[layer][i] = cn;
        hbuf[layer*SBLK*HP + s*HP + u] = sigf(ov)*tanhf(cn);
      }
      __syncthreads();
    }
  }
  #pragma unroll
  for (int i=0;i<4;i++){
    int id = tid + NTHR*i;
    int s = id>>7, u = id&127;
    feats[(s0+s)*HID + u] = hbuf[2*SBLK*HP + s*HP + u];
  }
}

// xl = in @ W^T ; optional input transform relu(in + pre_bias) (for GCN2 input)
template<int KOUT>
__global__ void gcn_gemm(const float* __restrict__ in, const float* __restrict__ W,
                         const float* __restrict__ pre_bias, float* __restrict__ out)
{
  int id  = blockIdx.x*256 + threadIdx.x;   // grid sized exactly R*KOUT/256
  int row = id / KOUT;
  int o   = id & (KOUT-1);
  const float4* a4 = (const float4*)(in + row*HID);
  const float4* w4 = (const float4*)(W + o*HID);
  float acc = 0.f;
  if (pre_bias){
    const float4* b4 = (const float4*)pre_bias;
    #pragma unroll 8
    for (int k=0;k<HID/4;k++){
      float4 av = a4[k], wv = w4[k], bv = b4[k];
      acc += fmaxf(av.x+bv.x,0.f)*wv.x + fmaxf(av.y+bv.y,0.f)*wv.y
           + fmaxf(av.z+bv.z,0.f)*wv.z + fmaxf(av.w+bv.w,0.f)*wv.w;
    }
  } else {
    #pragma unroll 8
    for (int k=0;k<HID/4;k++){
      float4 av = a4[k], wv = w4[k];
      acc += av.x*wv.x + av.y*wv.y + av.z*wv.z + av.w*wv.w;
    }
  }
  out[id] = acc;
}

// agg[b,dst,:] += xl[b,src,:] * dis[src]*dis[dst]; slot >= EE are self-loops
template<int KOUT>
__global__ void gcn_scatter(const float* __restrict__ xl, const int* __restrict__ ei,
                            const float* __restrict__ deg, float* __restrict__ agg)
{
  int e = blockIdx.x, bb = blockIdx.y, f = threadIdx.x;
  int s, d; float nm;
  if (e < EE){ s = ei[e]; d = ei[EE+e]; nm = rsqrtf(deg[s])*rsqrtf(deg[d]); }
  else { s = e - EE; d = s; nm = 1.0f/deg[s]; }
  atomicAdd(&agg[(bb*NN + d)*KOUT + f], xl[(bb*NN + s)*KOUT + f]*nm);
}

__global__ void deg_init(float* deg){
  int i = blockIdx.x*256 + threadIdx.x;
  if (i < NN) deg[i] = 1.0f;              // self-loop contribution
}
__global__ void deg_edges(const int* __restrict__ ei, float* deg){
  int e = blockIdx.x*256 + threadIdx.x;
  if (e < EE) atomicAdd(&deg[ei[EE+e]], 1.0f);
}

// out[b] = mean_n relu(agg2+b2) . cls_w + cls_b
__global__ void finalize(const float* __restrict__ agg2, const float* __restrict__ b2,
                         const float* __restrict__ clw, const float* __restrict__ clb,
                         float* __restrict__ out)
{
  __shared__ float red[256];
  int bb = blockIdx.x, tid = threadIdx.x;
  float acc = 0.f;
  for (int i = tid; i < NN*64; i += 256){
    int j = i & 63;
    float v = agg2[bb*NN*64 + i] + b2[j];
    acc += fmaxf(v, 0.f) * clw[j];
  }
  red[tid] = acc; __syncthreads();
  for (int sfd=128; sfd>0; sfd>>=1){
    if (tid < sfd) red[tid] += red[tid+sfd];
    __syncthreads();
  }
  if (tid==0) out[bb] = red[0]*(1.0f/NN) + clb[0];
}

extern "C" void kernel_launch(void* const* d_in, const int* in_sizes, int n_in,
                              void* d_out, int out_size, void* d_ws, size_t ws_size,
                              hipStream_t stream)
{
  const float* x    = (const float*)d_in[0];
  const int*   ei   = (const int*)  d_in[1];
  const float* wih0 = (const float*)d_in[2];
  const float* whh0 = (const float*)d_in[3];
  const float* bih0 = (const float*)d_in[4];
  const float* bhh0 = (const float*)d_in[5];
  const float* wih1 = (const float*)d_in[6];
  const float* whh1 = (const float*)d_in[7];
  const float* bih1 = (const float*)d_in[8];
  const float* bhh1 = (const float*)d_in[9];
  const float* wih2 = (const float*)d_in[10];
  const float* whh2 = (const float*)d_in[11];
  const float* bih2 = (const float*)d_in[12];
  const float* bhh2 = (const float*)d_in[13];
  const float* g1w  = (const float*)d_in[14];
  const float* g1b  = (const float*)d_in[15];
  const float* g2w  = (const float*)d_in[16];
  const float* g2b  = (const float*)d_in[17];
  const float* clw  = (const float*)d_in[18];
  const float* clb  = (const float*)d_in[19];
  float* out = (float*)d_out;

  char* ws = (char*)d_ws;
  float* feats = (float*)(ws);                 // [4096,128]  2 MB
  float* xl1   = (float*)(ws + 2097152);       // [8,512,128] 2 MB
  float* agg1  = (float*)(ws + 4194304);       // [8,512,128] 2 MB
  float* xl2   = (float*)(ws + 6291456);       // [8,512,64]  1 MB
  float* agg2  = (float*)(ws + 7340032);       // [8,512,64]  1 MB
  float* deg   = (float*)(ws + 8388608);       // [512]

  hipMemsetAsync(agg1, 0, 2097152, stream);
  hipMemsetAsync(agg2, 0, 1048576, stream);
  deg_init <<<2, 256, 0, stream>>>(deg);
  deg_edges<<<EE/256, 256, 0, stream>>>(ei, deg);

  lstm_scan<<<256, NTHR, 0, stream>>>(x, wih0, whh0, bih0, bhh0,
      wih1, whh1, bih1, bhh1, wih2, whh2, bih2, bhh2, feats);

  gcn_gemm<128><<<(4096*128)/256, 256, 0, stream>>>(feats, g1w, nullptr, xl1);
  gcn_scatter<128><<<dim3(EE+NN, NB), 128, 0, stream>>>(xl1, ei, deg, agg1);
  gcn_gemm<64><<<(4096*64)/256, 256, 0, stream>>>(agg1, g2w, g1b, xl2);
  gcn_scatter<64><<<dim3(EE+NN, NB), 64, 0, stream>>>(xl2, ei, deg, agg2);
  finalize<<<NB, 256, 0, stream>>>(agg2, g2b, clw, clb, out);
}

// Round 2
// 4690.291 us; speedup vs baseline: 2.0610x; 2.0610x over previous
//
#include <hip/hip_runtime.h>

#define TT   64
#define NB   8
#define NN   512
#define HID  128
#define G4   512
#define EE   8192
#define SBLK 16
#define NTHR 512
#define KC   16
#define HP   132                 // hbuf row pitch (floats), 16B-aligned, 2-way max
#define CHUNKF (G4*KC)           // 8192 floats = 32KB per chunk buffer

__device__ __forceinline__ float sigf(float x){ return 1.0f/(1.0f+expf(-x)); }

// async global->LDS, 16B per lane; LDS dest = wave-uniform base + lane*16
__device__ __forceinline__ void gload16(const float* g, float* l){
  __builtin_amdgcn_global_load_lds(
      (const __attribute__((address_space(1))) void*)g,
      (__attribute__((address_space(3))) void*)l, 16, 0, 0);
}

// Fused 3-layer LSTM scan. 256 blocks x 512 thr, 16 seqs/block, all 64 steps.
// Thread (u, sq) owns gates {u,u+128,u+256,u+384} (i,f,g,o of unit u) for 4 seqs.
// Weights DMA-streamed L2->LDS in double-buffered 32KB chunks, XOR-swizzled.
__global__ __launch_bounds__(NTHR,2) void lstm_scan(
    const float* __restrict__ x,    const float* __restrict__ wih0,
    const float* __restrict__ whh0, const float* __restrict__ bih0, const float* __restrict__ bhh0,
    const float* __restrict__ wih1, const float* __restrict__ whh1,
    const float* __restrict__ bih1, const float* __restrict__ bhh1,
    const float* __restrict__ wih2, const float* __restrict__ whh2,
    const float* __restrict__ bih2, const float* __restrict__ bhh2,
    float* __restrict__ feats)
{
  __shared__ __align__(16) float Wbuf[2*CHUNKF];     // 64 KB
  __shared__ __align__(16) float hbuf[3*SBLK*HP];    // 24.75 KB
  __shared__ float xbuf[SBLK];

  const int tid  = threadIdx.x;
  const int lane = tid & 63, wv = tid >> 6;
  const int u    = tid >> 2, sq = tid & 3;
  const int s0   = blockIdx.x * SBLK;
  const int b    = s0 >> 9, n0 = s0 & (NN-1);

  for (int i = tid; i < 3*SBLK*HP; i += NTHR) hbuf[i] = 0.0f;

  // biases + wih0 column in registers (constant-indexed, no scratch)
  float bj0[4], bj1[4], bj2[4], w0g[4];
  #pragma unroll
  for (int j=0;j<4;j++){
    bj0[j] = bih0[u+128*j] + bhh0[u+128*j];
    bj1[j] = bih1[u+128*j] + bhh1[u+128*j];
    bj2[j] = bih2[u+128*j] + bhh2[u+128*j];
    w0g[j] = wih0[u+128*j];
  }

  // per-thread DMA constants: call i covers rows C*16..C*16+15, C = wv*4+i
  int gofs[4], lofs[4];
  #pragma unroll
  for (int i=0;i<4;i++){
    int C  = wv*4 + i;
    int r  = C*16 + (lane>>2);             // gate row in chunk
    int kk = (lane&3) ^ ((r>>1)&3);        // source 16B-block for this LDS slot
    gofs[i] = r*HID + kk*4;                // float offset within matrix (+k0)
    lofs[i] = C*256;                       // float offset within chunk buffer
  }

  const int uswz = (u>>1)&3;               // read-side swizzle (j-independent)
  int wrow[4];
  #pragma unroll
  for (int j=0;j<4;j++) wrow[j] = (u+128*j)*KC;

  float acc[4][4];
  float cst0[4]={0,0,0,0}, cst1[4]={0,0,0,0}, cst2[4]={0,0,0,0};
  float hlast[4]={0,0,0,0};

  // prologue: DMA chunk 0 (whh0, k0=0) -> buf 0
  #pragma unroll
  for (int i=0;i<4;i++) gload16(whh0 + gofs[i], &Wbuf[lofs[i]]);

  #pragma unroll 1
  for (int t=0;t<TT;t++){
    if (tid < SBLK) xbuf[tid] = x[(b*TT + t)*NN + n0 + tid];
    #pragma unroll 1
    for (int c=0;c<40;c++){
      __syncthreads();                     // drains DMA(c); protects buf reuse
      // prefetch chunk c+1 into other buffer (async, completes during compute)
      int nx = c + 1; if (nx == 40) nx = 0;
      {
        const float* m;
        switch (nx>>3){ case 0: m=whh0; break; case 1: m=wih1; break;
                        case 2: m=whh1; break; case 3: m=wih2; break;
                        default: m=whh2; }
        const float* msrc = m + (nx&7)*KC;
        float* dst = &Wbuf[(nx&1)*CHUNKF];
        #pragma unroll
        for (int i=0;i<4;i++) gload16(msrc + gofs[i], dst + lofs[i]);
      }
      if      (c==0 ){ for (int j=0;j<4;j++) for (int i=0;i<4;i++) acc[j][i]=bj0[j]; }
      else if (c==8 ){ for (int j=0;j<4;j++) for (int i=0;i<4;i++) acc[j][i]=bj1[j]; }
      else if (c==24){ for (int j=0;j<4;j++) for (int i=0;i<4;i++) acc[j][i]=bj2[j]; }

      const int hl = (c<16)?0:((c<32)?1:2);
      const int k0 = (c&7)*KC;
      const float* wb  = &Wbuf[(c&1)*CHUNKF];
      const float* hp0 = &hbuf[(hl*SBLK + 4*sq+0)*HP + k0];
      const float* hp1 = hp0 + HP;
      const float* hp2 = hp1 + HP;
      const float* hp3 = hp2 + HP;

      #pragma unroll
      for (int kg=0;kg<4;kg++){
        const int kgp = ((kg ^ uswz) << 2);
        float4 w[4], hv[4];
        w[0] = *(const float4*)(wb + wrow[0] + kgp);
        w[1] = *(const float4*)(wb + wrow[1] + kgp);
        w[2] = *(const float4*)(wb + wrow[2] + kgp);
        w[3] = *(const float4*)(wb + wrow[3] + kgp);
        hv[0] = *(const float4*)(hp0 + 4*kg);
        hv[1] = *(const float4*)(hp1 + 4*kg);
        hv[2] = *(const float4*)(hp2 + 4*kg);
        hv[3] = *(const float4*)(hp3 + 4*kg);
        #pragma unroll
        for (int j=0;j<4;j++)
          #pragma unroll
          for (int i=0;i<4;i++)
            acc[j][i] += w[j].x*hv[i].x + w[j].y*hv[i].y
                       + w[j].z*hv[i].z + w[j].w*hv[i].w;
      }

      #define CELL(Lc, CST, XTERM, LAST)                                        \
        { __syncthreads();                                                      \
          _Pragma("unroll")                                                     \
          for (int i=0;i<4;i++){                                                \
            float iv=acc[0][i], fv=acc[1][i], gv=acc[2][i], ov=acc[3][i];       \
            if (XTERM){ float xv=xbuf[4*sq+i]; iv+=xv*w0g[0]; fv+=xv*w0g[1];    \
                        gv+=xv*w0g[2]; ov+=xv*w0g[3]; }                         \
            float cn = sigf(fv)*CST[i] + sigf(iv)*tanhf(gv);                    \
            CST[i]=cn; float hn = sigf(ov)*tanhf(cn);                           \
            hbuf[((Lc)*SBLK + 4*sq+i)*HP + u] = hn;                             \
            if (LAST) hlast[i]=hn; } }

      if      (c==7 ) CELL(0, cst0, 1, 0)
      else if (c==23) CELL(1, cst1, 0, 0)
      else if (c==39) CELL(2, cst2, 0, 1)
      #undef CELL
    }
  }
  #pragma unroll
  for (int i=0;i<4;i++)
    feats[(s0 + 4*sq + i)*HID + u] = hlast[i];
}

// xl = in @ W^T ; optional input transform relu(in + pre_bias)
template<int KOUT>
__global__ void gcn_gemm(const float* __restrict__ in, const float* __restrict__ W,
                         const float* __restrict__ pre_bias, float* __restrict__ out)
{
  int id  = blockIdx.x*256 + threadIdx.x;
  int row = id / KOUT;
  int o   = id & (KOUT-1);
  const float4* a4 = (const float4*)(in + row*HID);
  const float4* w4 = (const float4*)(W + o*HID);
  float acc = 0.f;
  if (pre_bias){
    const float4* b4 = (const float4*)pre_bias;
    #pragma unroll 8
    for (int k=0;k<HID/4;k++){
      float4 av=a4[k], wv=w4[k], bv=b4[k];
      acc += fmaxf(av.x+bv.x,0.f)*wv.x + fmaxf(av.y+bv.y,0.f)*wv.y
           + fmaxf(av.z+bv.z,0.f)*wv.z + fmaxf(av.w+bv.w,0.f)*wv.w;
    }
  } else {
    #pragma unroll 8
    for (int k=0;k<HID/4;k++){
      float4 av=a4[k], wv=w4[k];
      acc += av.x*wv.x + av.y*wv.y + av.z*wv.z + av.w*wv.w;
    }
  }
  out[id] = acc;
}

__global__ void deg_init(float* deg){
  int i = blockIdx.x*256 + threadIdx.x;
  if (i < NN) deg[i] = 1.0f;             // self-loop
}
__global__ void deg_edges(const int* __restrict__ ei, float* deg){
  int e = blockIdx.x*256 + threadIdx.x;
  if (e < EE) atomicAdd(&deg[ei[EE+e]], 1.0f);
}
// dense normalized adjacency: A[dst][src] += dis[src]*dis[dst]; diag += 1/deg
__global__ void build_A(const int* __restrict__ ei, const float* __restrict__ deg,
                        float* __restrict__ A){
  int e = blockIdx.x*256 + threadIdx.x;
  if (e < EE){
    int s = ei[e], d = ei[EE+e];
    atomicAdd(&A[d*NN+s], rsqrtf(deg[s])*rsqrtf(deg[d]));
  } else if (e < EE+NN){
    int n = e - EE;
    atomicAdd(&A[n*NN+n], 1.0f/deg[n]);
  }
}

// Y[b,n,:] = sum_m A[n,m] * X[b,m,:]  (dense aggregation, 16 rows/block)
template<int KOUT>
__global__ __launch_bounds__(512) void gcn_agg(const float* __restrict__ A,
    const float* __restrict__ X, float* __restrict__ Y)
{
  const int F4 = KOUT/4;                   // 32 or 16
  const int TN = 16;
  __shared__ __align__(16) float As[TN*NN];
  const int b = blockIdx.x, n0 = blockIdx.y*TN;
  const int tid = threadIdx.x;
  const int f4 = tid & (F4-1), nr = tid / F4;
  for (int i = tid; i < TN*NN; i += TN*F4) As[i] = A[n0*NN + i];
  __syncthreads();
  const float* Xb = X + b*NN*KOUT + f4*4;
  const float* Ar = As + nr*NN;
  float4 s = {0,0,0,0};
  #pragma unroll 4
  for (int m=0;m<NN;m++){
    float a = Ar[m];
    float4 xv = *(const float4*)(Xb + m*KOUT);
    s.x += a*xv.x; s.y += a*xv.y; s.z += a*xv.z; s.w += a*xv.w;
  }
  *(float4*)(Y + (b*NN + n0 + nr)*KOUT + f4*4) = s;
}

// out[b] = mean_n relu(agg2+b2) . cls_w + cls_b
__global__ void finalize(const float* __restrict__ agg2, const float* __restrict__ b2,
                         const float* __restrict__ clw, const float* __restrict__ clb,
                         float* __restrict__ out)
{
  __shared__ float red[256];
  int bb = blockIdx.x, tid = threadIdx.x;
  float acc = 0.f;
  for (int i = tid; i < NN*64; i += 256){
    int j = i & 63;
    float v = agg2[bb*NN*64 + i] + b2[j];
    acc += fmaxf(v, 0.f) * clw[j];
  }
  red[tid] = acc; __syncthreads();
  for (int sfd=128; sfd>0; sfd>>=1){
    if (tid < sfd) red[tid] += red[tid+sfd];
    __syncthreads();
  }
  if (tid==0) out[bb] = red[0]*(1.0f/NN) + clb[0];
}

extern "C" void kernel_launch(void* const* d_in, const int* in_sizes, int n_in,
                              void* d_out, int out_size, void* d_ws, size_t ws_size,
                              hipStream_t stream)
{
  const float* x    = (const float*)d_in[0];
  const int*   ei   = (const int*)  d_in[1];
  const float* wih0 = (const float*)d_in[2];
  const float* whh0 = (const float*)d_in[3];
  const float* bih0 = (const float*)d_in[4];
  const float* bhh0 = (const float*)d_in[5];
  const float* wih1 = (const float*)d_in[6];
  const float* whh1 = (const float*)d_in[7];
  const float* bih1 = (const float*)d_in[8];
  const float* bhh1 = (const float*)d_in[9];
  const float* wih2 = (const float*)d_in[10];
  const float* whh2 = (const float*)d_in[11];
  const float* bih2 = (const float*)d_in[12];
  const float* bhh2 = (const float*)d_in[13];
  const float* g1w  = (const float*)d_in[14];
  const float* g1b  = (const float*)d_in[15];
  const float* g2w  = (const float*)d_in[16];
  const float* g2b  = (const float*)d_in[17];
  const float* clw  = (const float*)d_in[18];
  const float* clb  = (const float*)d_in[19];
  float* out = (float*)d_out;

  char* ws = (char*)d_ws;
  float* feats = (float*)(ws);                 // [4096,128]  2 MB
  float* xl1   = (float*)(ws + 2097152);       // [8,512,128] 2 MB
  float* agg1  = (float*)(ws + 4194304);       // [8,512,128] 2 MB
  float* xl2   = (float*)(ws + 6291456);       // [8,512,64]  1 MB
  float* agg2  = (float*)(ws + 7340032);       // [8,512,64]  1 MB
  float* A     = (float*)(ws + 8388608);       // [512,512]   1 MB
  float* deg   = (float*)(ws + 9437184);       // [512]

  hipMemsetAsync(A, 0, NN*NN*sizeof(float), stream);
  deg_init <<<2, 256, 0, stream>>>(deg);
  deg_edges<<<EE/256, 256, 0, stream>>>(ei, deg);
  build_A  <<<(EE+NN+255)/256, 256, 0, stream>>>(ei, deg, A);

  lstm_scan<<<256, NTHR, 0, stream>>>(x, wih0, whh0, bih0, bhh0,
      wih1, whh1, bih1, bhh1, wih2, whh2, bih2, bhh2, feats);

  gcn_gemm<128><<<(4096*128)/256, 256, 0, stream>>>(feats, g1w, nullptr, xl1);
  gcn_agg<128><<<dim3(NB, NN/16), 512, 0, stream>>>(A, xl1, agg1);
  gcn_gemm<64><<<(4096*64)/256, 256, 0, stream>>>(agg1, g2w, g1b, xl2);
  gcn_agg<64><<<dim3(NB, NN/16), 256, 0, stream>>>(A, xl2, agg2);
  finalize<<<NB, 256, 0, stream>>>(agg2, g2b, clw, clb, out);
}